// Round 9
// baseline (259.250 us; speedup 1.0000x reference)
//
#include <hip/hip_runtime.h>
#include <cmath>

#define NODES 40000
#define NPAD  40960            // padded rows: 640 blocks x 64 rows
#define EDGES 600000
#define HD    128
#define CAP   80               // bucket capacity (Poisson mean 15; P(>80) ~ 0)
#define BN_EPS 1e-5f
#define PK    (HD + 8)

typedef short bf16x8 __attribute__((ext_vector_type(8)));
typedef float f32x4  __attribute__((ext_vector_type(4)));
typedef unsigned short u16;
typedef unsigned int   u32;

__device__ __forceinline__ float bf2f(u16 u) {
  union { u32 i; float f; } v; v.i = ((u32)u) << 16; return v.f;
}
__device__ __forceinline__ u16 f2bf(float f) {
  union { float f; u32 i; } v; v.f = f;
  u32 r = v.i + 0x7FFF + ((v.i >> 16) & 1);   // RNE
  return (u16)(r >> 16);
}
__device__ __forceinline__ float elu(float x) {
  return x > 0.f ? x : __expf(x) - 1.f;
}

struct WPrep { const float* s[8]; u16* d[8]; };

// ---------------- one-time prep: cast x | transpose weights | zero cnt -----
__global__ __launch_bounds__(256) void prep_all(const float4* __restrict__ x4,
                                                ushort4* __restrict__ xb4,
                                                WPrep p, int* __restrict__ cnt) {
  const int bid = blockIdx.x;
  const int tid = threadIdx.x;
  if (bid < 5000) {
    int i = bid * 256 + tid;
    float4 v = x4[i];
    ushort4 o;
    o.x = f2bf(v.x); o.y = f2bf(v.y); o.z = f2bf(v.z); o.w = f2bf(v.w);
    xb4[i] = o;
  } else if (bid < 5128) {
    int b = bid - 5000;
    int m = b >> 4, xx = b & 15;
    int N = (m == 7) ? 64 : 128;
    int tiles_n = N / 32;
    int tx = xx % tiles_n, tk = xx / tiles_n;
    if (tk >= 4) return;
    __shared__ float t[32][33];
    int c = tid & 31, r8 = tid >> 5;
    const float* s = p.s[m];
    for (int rr = 0; rr < 32; rr += 8)
      t[rr + r8][c] = s[(size_t)(tk * 32 + rr + r8) * N + tx * 32 + c];
    __syncthreads();
    u16* d = p.d[m];
    for (int rr = 0; rr < 32; rr += 8)
      d[(size_t)(tx * 32 + rr + r8) * HD + tk * 32 + c] = f2bf(t[c][rr + r8]);
  } else {
    int i = (bid - 5128) * 256 + tid;
    if (i < NODES) cnt[i] = 0;
  }
}

// ---------------- bucket fill (u16 sources: ids < 40000 < 65536) ----------
__global__ __launch_bounds__(256) void bucket_fill(const int* __restrict__ ei,
                                                   int* __restrict__ cnt,
                                                   u16* __restrict__ bucket) {
  int e = blockIdx.x * 256 + threadIdx.x;
  if (e >= EDGES) return;
  int s = ei[e];
  int d = ei[EDGES + e];
  int pos = atomicAdd(&cnt[d], 1);
  if (pos < CAP) bucket[d * CAP + pos] = (u16)s;
}

// ---- in-kernel gather, quarter-wave per node, DYNAMIC work queue (R7) ----
// R7 model refinement: gather is pattern-BW/imbalance-bound, not in-flight
// bound. Fixed 4-nodes-per-quarter-wave made block time = max over 16
// quarter-waves of Poisson-sum(60) (~+30% tail). Dynamic LDS-counter queue
// balances to ~mean + 1-node granularity. Per-node accumulation order is
// unchanged (scheduling permutes WHO processes a node, not the within-node
// order) -> bit-identical numerics.
__device__ __forceinline__ void unpack_init(float* a, uint4 v) {
  a[0] = bf2f((u16)v.x); a[1] = bf2f((u16)(v.x >> 16));
  a[2] = bf2f((u16)v.y); a[3] = bf2f((u16)(v.y >> 16));
  a[4] = bf2f((u16)v.z); a[5] = bf2f((u16)(v.z >> 16));
  a[6] = bf2f((u16)v.w); a[7] = bf2f((u16)(v.w >> 16));
}
__device__ __forceinline__ void unpack_add(float* a, uint4 v) {
  a[0] += bf2f((u16)v.x); a[1] += bf2f((u16)(v.x >> 16));
  a[2] += bf2f((u16)v.y); a[3] += bf2f((u16)(v.y >> 16));
  a[4] += bf2f((u16)v.z); a[5] += bf2f((u16)(v.z >> 16));
  a[6] += bf2f((u16)v.w); a[7] += bf2f((u16)(v.w >> 16));
}

__device__ __forceinline__ void gather64(const u16* __restrict__ x,
                                         const int* __restrict__ cnt,
                                         const u16* __restrict__ bucket,
                                         int node0, int tid,
                                         u16 (*L)[PK], int* __restrict__ wq) {
  const int ql = tid & 15;             // lane within quarter-wave
  const int qwl = (tid >> 4) & 3;      // quarter index within this wave
  for (;;) {
    int n = 0;
    if (ql == 0) n = atomicAdd(wq, 1);
    n = __shfl(n, qwl * 16, 64);       // broadcast from quarter leader
    if (n >= 64) break;
    const int node = node0 + n;
    float a[8];
    if (node < NODES) {
      const int i0 = node * CAP;
      // three independent loads, issued back-to-back
      uint4 self = ((const uint4*)(x + (size_t)node * HD))[ql];
      int sv = bucket[i0 + ql];        // chunk-0 slots (ql<16<=CAP), no cnt dep
      int deg = cnt[node];
      if (deg > CAP) deg = CAP;
      unpack_init(a, self);
      for (int c0 = 0; c0 < deg; c0 += 16) {
        int m = deg - c0;
        if (m > 16) m = 16;
        for (int j = 0; j < m; j += 8) {
          int idx[8];
          uint4 uu[8];
#pragma unroll
          for (int jj = 0; jj < 8; ++jj) {
            int src = j + jj < m ? j + jj : 0;
            idx[jj] = __shfl(sv, src, 16);
          }
#pragma unroll
          for (int jj = 0; jj < 8; ++jj)
            uu[jj] = ((const uint4*)(x + (size_t)idx[jj] * HD))[ql];
#pragma unroll
          for (int jj = 0; jj < 8; ++jj)
            if (j + jj < m) unpack_add(a, uu[jj]);
        }
        int nc = c0 + 16;              // next slot chunk (deg>16); CAP clamp
        if (nc < deg) {
          int ad = nc + ql;
          sv = bucket[i0 + (ad < CAP ? ad : 0)];
        }
      }
    } else {
#pragma unroll
      for (int k = 0; k < 8; ++k) a[k] = 0.f;
    }
    uint4 pk;
    pk.x = (u32)f2bf(a[0]) | ((u32)f2bf(a[1]) << 16);
    pk.y = (u32)f2bf(a[2]) | ((u32)f2bf(a[3]) << 16);
    pk.z = (u32)f2bf(a[4]) | ((u32)f2bf(a[5]) << 16);
    pk.w = (u32)f2bf(a[6]) | ((u32)f2bf(a[7]) << 16);
    *(uint4*)&L[128 + n][ql * 8] = pk;
  }
}

// ------------- fused layer: gather + ELU(BN(A@W1+b1))@W2+b2, ELU ----------
__global__ __launch_bounds__(256) void gin_layer(
    const u16* __restrict__ xin, const int* __restrict__ cnt,
    const u16* __restrict__ bucket, const u16* __restrict__ W1t,
    const float* __restrict__ b1, const float* __restrict__ g,
    const float* __restrict__ bt, const float* __restrict__ mu,
    const float* __restrict__ vr, const u16* __restrict__ W2t,
    const float* __restrict__ b2, u16* __restrict__ xout) {
  __shared__ u16 L[192][PK];
  __shared__ int wq;

  const int tid = threadIdx.x;
  const int wv = tid >> 6, lane = tid & 63;
  const int col = lane & 15, kg = lane >> 4;
  const int strip = blockIdx.x * 4 + wv;
  const int hrow = 128 + wv * 16;

  if (tid == 0) wq = 0;
  __syncthreads();                     // cheap: nothing outstanding yet

  // stage W1 (loads issued first; latency hides under gather)
#pragma unroll
  for (int t = tid; t < 128 * 16; t += 256) {
    int r = t >> 4, c8 = t & 15;
    *(bf16x8*)&L[r][c8 * 8] = *(const bf16x8*)(W1t + (size_t)r * HD + c8 * 8);
  }
  gather64(xin, cnt, bucket, blockIdx.x * 64, tid, L, &wq);
  __syncthreads();

  // GEMM1 (A from LDS)
  f32x4 acc[8];
#pragma unroll
  for (int t = 0; t < 8; ++t) acc[t] = (f32x4){0.f, 0.f, 0.f, 0.f};
#pragma unroll
  for (int kk = 0; kk < HD; kk += 32) {
    bf16x8 av = *(const bf16x8*)&L[hrow + col][kk + kg * 8];
#pragma unroll
    for (int t = 0; t < 8; ++t) {
      bf16x8 bv = *(const bf16x8*)&L[t * 16 + col][kk + kg * 8];
      acc[t] = __builtin_amdgcn_mfma_f32_16x16x32_bf16(av, bv, acc[t], 0, 0, 0);
    }
  }
  __syncthreads();  // all waves done reading W1

  // stage W2 into rows 0-127; write H (BN+ELU) over own A strip
#pragma unroll
  for (int t = tid; t < 128 * 16; t += 256) {
    int r = t >> 4, c8 = t & 15;
    *(bf16x8*)&L[r][c8 * 8] = *(const bf16x8*)(W2t + (size_t)r * HD + c8 * 8);
  }
#pragma unroll
  for (int t = 0; t < 8; ++t) {
    int c = t * 16 + col;
    float rs = rsqrtf(vr[c] + BN_EPS) * g[c];
    float bb = bt[c] + (b1[c] - mu[c]) * rs;
#pragma unroll
    for (int r = 0; r < 4; ++r)
      L[hrow + kg * 4 + r][c] = f2bf(elu(acc[t][r] * rs + bb));
  }
  __syncthreads();

  // GEMM2
  f32x4 acc2[8];
#pragma unroll
  for (int t = 0; t < 8; ++t) acc2[t] = (f32x4){0.f, 0.f, 0.f, 0.f};
#pragma unroll
  for (int kk = 0; kk < HD; kk += 32) {
    bf16x8 av = *(const bf16x8*)&L[hrow + col][kk + kg * 8];
#pragma unroll
    for (int t = 0; t < 8; ++t) {
      bf16x8 bv = *(const bf16x8*)&L[t * 16 + col][kk + kg * 8];
      acc2[t] = __builtin_amdgcn_mfma_f32_16x16x32_bf16(av, bv, acc2[t], 0, 0, 0);
    }
  }
#pragma unroll
  for (int t = 0; t < 8; ++t) {
    int c = t * 16 + col;
    float bb = b2[c];
#pragma unroll
    for (int r = 0; r < 4; ++r)
      L[hrow + kg * 4 + r][c] = f2bf(elu(acc2[t][r] + bb));
  }
  {
    int r0 = lane >> 4, seg = lane & 15;
#pragma unroll
    for (int rr = 0; rr < 16; rr += 4) {
      int row = rr + r0;
      *(float4*)((char*)(xout + (size_t)(strip * 16 + row) * HD) + seg * 16) =
          *(const float4*)((const char*)&L[hrow + row][0] + seg * 16);
    }
  }
}

// ---- fused layer-3 + head: gather + 4 chained GEMMs ----------------------
__global__ __launch_bounds__(256) void gin_head(
    const u16* __restrict__ xin, const int* __restrict__ cnt,
    const u16* __restrict__ bucket, const u16* __restrict__ W1t,
    const float* __restrict__ b1, const float* __restrict__ g,
    const float* __restrict__ bt, const float* __restrict__ mu,
    const float* __restrict__ vr, const u16* __restrict__ W2t,
    const float* __restrict__ b2, const u16* __restrict__ L1t,
    const float* __restrict__ lb1, const u16* __restrict__ L2t,
    const float* __restrict__ lb2, float* __restrict__ out) {
  __shared__ u16 L[192][PK];
  __shared__ int wq;

  const int tid = threadIdx.x;
  const int wv = tid >> 6, lane = tid & 63;
  const int col = lane & 15, kg = lane >> 4;
  const int strip = blockIdx.x * 4 + wv;
  const int hrow = 128 + wv * 16;

  if (tid == 0) wq = 0;
  __syncthreads();

#pragma unroll
  for (int t = tid; t < 128 * 16; t += 256) {
    int r = t >> 4, c8 = t & 15;
    *(bf16x8*)&L[r][c8 * 8] = *(const bf16x8*)(W1t + (size_t)r * HD + c8 * 8);
  }
  gather64(xin, cnt, bucket, blockIdx.x * 64, tid, L, &wq);
  __syncthreads();

  // GEMM1 (BN+ELU)
  f32x4 acc[8];
#pragma unroll
  for (int t = 0; t < 8; ++t) acc[t] = (f32x4){0.f, 0.f, 0.f, 0.f};
#pragma unroll
  for (int kk = 0; kk < HD; kk += 32) {
    bf16x8 av = *(const bf16x8*)&L[hrow + col][kk + kg * 8];
#pragma unroll
    for (int t = 0; t < 8; ++t) {
      bf16x8 bv = *(const bf16x8*)&L[t * 16 + col][kk + kg * 8];
      acc[t] = __builtin_amdgcn_mfma_f32_16x16x32_bf16(av, bv, acc[t], 0, 0, 0);
    }
  }
  __syncthreads();
#pragma unroll
  for (int t = tid; t < 128 * 16; t += 256) {   // stage W2
    int r = t >> 4, c8 = t & 15;
    *(bf16x8*)&L[r][c8 * 8] = *(const bf16x8*)(W2t + (size_t)r * HD + c8 * 8);
  }
#pragma unroll
  for (int t = 0; t < 8; ++t) {
    int c = t * 16 + col;
    float rs = rsqrtf(vr[c] + BN_EPS) * g[c];
    float bb = bt[c] + (b1[c] - mu[c]) * rs;
#pragma unroll
    for (int r = 0; r < 4; ++r)
      L[hrow + kg * 4 + r][c] = f2bf(elu(acc[t][r] * rs + bb));
  }
  __syncthreads();

  // GEMM2 (+b2, ELU)
#pragma unroll
  for (int t = 0; t < 8; ++t) acc[t] = (f32x4){0.f, 0.f, 0.f, 0.f};
#pragma unroll
  for (int kk = 0; kk < HD; kk += 32) {
    bf16x8 av = *(const bf16x8*)&L[hrow + col][kk + kg * 8];
#pragma unroll
    for (int t = 0; t < 8; ++t) {
      bf16x8 bv = *(const bf16x8*)&L[t * 16 + col][kk + kg * 8];
      acc[t] = __builtin_amdgcn_mfma_f32_16x16x32_bf16(av, bv, acc[t], 0, 0, 0);
    }
  }
  __syncthreads();
#pragma unroll
  for (int t = tid; t < 128 * 16; t += 256) {   // stage lin1
    int r = t >> 4, c8 = t & 15;
    *(bf16x8*)&L[r][c8 * 8] = *(const bf16x8*)(L1t + (size_t)r * HD + c8 * 8);
  }
#pragma unroll
  for (int t = 0; t < 8; ++t) {
    int c = t * 16 + col;
    float bb = b2[c];
#pragma unroll
    for (int r = 0; r < 4; ++r)
      L[hrow + kg * 4 + r][c] = f2bf(elu(acc[t][r] + bb));
  }
  __syncthreads();

  // LIN1 (+lb1, ELU)
#pragma unroll
  for (int t = 0; t < 8; ++t) acc[t] = (f32x4){0.f, 0.f, 0.f, 0.f};
#pragma unroll
  for (int kk = 0; kk < HD; kk += 32) {
    bf16x8 av = *(const bf16x8*)&L[hrow + col][kk + kg * 8];
#pragma unroll
    for (int t = 0; t < 8; ++t) {
      bf16x8 bv = *(const bf16x8*)&L[t * 16 + col][kk + kg * 8];
      acc[t] = __builtin_amdgcn_mfma_f32_16x16x32_bf16(av, bv, acc[t], 0, 0, 0);
    }
  }
  __syncthreads();
#pragma unroll
  for (int t = tid; t < 64 * 16; t += 256) {    // stage lin2 (64 rows)
    int r = t >> 4, c8 = t & 15;
    *(bf16x8*)&L[r][c8 * 8] = *(const bf16x8*)(L2t + (size_t)r * HD + c8 * 8);
  }
#pragma unroll
  for (int t = 0; t < 8; ++t) {
    int c = t * 16 + col;
    float bb = lb1[c];
#pragma unroll
    for (int r = 0; r < 4; ++r)
      L[hrow + kg * 4 + r][c] = f2bf(elu(acc[t][r] + bb));
  }
  __syncthreads();

  // LIN2 (+lb2) -> fp32 out [.][64]
  f32x4 acc2[4];
#pragma unroll
  for (int t = 0; t < 4; ++t) acc2[t] = (f32x4){0.f, 0.f, 0.f, 0.f};
#pragma unroll
  for (int kk = 0; kk < HD; kk += 32) {
    bf16x8 av = *(const bf16x8*)&L[hrow + col][kk + kg * 8];
#pragma unroll
    for (int t = 0; t < 4; ++t) {
      bf16x8 bv = *(const bf16x8*)&L[t * 16 + col][kk + kg * 8];
      acc2[t] = __builtin_amdgcn_mfma_f32_16x16x32_bf16(av, bv, acc2[t], 0, 0, 0);
    }
  }
#pragma unroll
  for (int t = 0; t < 4; ++t) {
    int c = t * 16 + col;
    float bb = lb2[c];
#pragma unroll
    for (int r = 0; r < 4; ++r)
      ((float*)&L[hrow + kg * 4 + r][0])[c] = acc2[t][r] + bb;
  }
  if (strip < NODES / 16) {            // real strips only (grid padded)
    int r0 = lane >> 4, seg = lane & 15;
#pragma unroll
    for (int rr = 0; rr < 16; rr += 4) {
      int row = rr + r0;
      *(float4*)((char*)(out + (size_t)(strip * 16 + row) * 64) + seg * 16) =
          *(const float4*)((const char*)&L[hrow + row][0] + seg * 16);
    }
  }
}

extern "C" void kernel_launch(void* const* d_in, const int* in_sizes, int n_in,
                              void* d_out, int out_size, void* d_ws, size_t ws_size,
                              hipStream_t stream) {
  const float* x = (const float*)d_in[0];
  const int* ei  = (const int*)d_in[1];
  const float* p[30];
  for (int i = 0; i < 30 && i < n_in; ++i) p[i] = (const float*)d_in[i];

  const size_t FEATP = (size_t)NPAD * HD;
  u16* xb0  = (u16*)d_ws;
  u16* xb1  = xb0 + FEATP;           // ping-pong
  u16* wt   = xb1 + FEATP;
  u16* wts[8];
  for (int m = 0; m < 8; ++m) wts[m] = wt + (size_t)m * HD * HD;
  int* cnt     = (int*)(wt + 8 * HD * HD);
  u16* bucket  = (u16*)(cnt + NODES);  // NODES*CAP u16 = 6.4 MB

  dim3 blk(256);
  const int edgeGrid = (EDGES + 255) / 256;   // 2344
  const int layerGrid = NPAD / 64;            // 640

  WPrep wp;
  const int widx[8] = {2, 8, 10, 16, 18, 24, 26, 28};
  for (int m = 0; m < 8; ++m) { wp.s[m] = p[widx[m]]; wp.d[m] = wts[m]; }
  prep_all<<<5285, blk, 0, stream>>>((const float4*)x, (ushort4*)xb0, wp, cnt);
  bucket_fill<<<edgeGrid, blk, 0, stream>>>(ei, cnt, bucket);

  gin_layer<<<layerGrid, blk, 0, stream>>>(
      xb0, cnt, bucket, wts[0], p[3], p[4], p[5], p[6], p[7], wts[1], p[9], xb1);
  gin_layer<<<layerGrid, blk, 0, stream>>>(
      xb1, cnt, bucket, wts[2], p[11], p[12], p[13], p[14], p[15], wts[3], p[17], xb0);
  gin_head<<<layerGrid, blk, 0, stream>>>(
      xb0, cnt, bucket, wts[4], p[19], p[20], p[21], p[22], p[23], wts[5], p[25],
      wts[6], p[27], wts[7], p[29], (float*)d_out);
}

// Round 10
// 259.210 us; speedup vs baseline: 1.0002x; 1.0002x over previous
//
#include <hip/hip_runtime.h>
#include <cmath>

#define NODES 40000
#define NPAD  40960            // padded rows: 640 blocks x 64 rows
#define EDGES 600000
#define HD    128
#define CAP   80               // bucket capacity (Poisson mean 15; P(>80) ~ 0)
#define BN_EPS 1e-5f
#define PK    (HD + 8)

typedef short bf16x8 __attribute__((ext_vector_type(8)));
typedef float f32x4  __attribute__((ext_vector_type(4)));
typedef unsigned short u16;
typedef unsigned int   u32;

__device__ __forceinline__ float bf2f(u16 u) {
  union { u32 i; float f; } v; v.i = ((u32)u) << 16; return v.f;
}
__device__ __forceinline__ u16 f2bf(float f) {
  union { float f; u32 i; } v; v.f = f;
  u32 r = v.i + 0x7FFF + ((v.i >> 16) & 1);   // RNE
  return (u16)(r >> 16);
}
__device__ __forceinline__ float elu(float x) {
  return x > 0.f ? x : __expf(x) - 1.f;
}

struct WPrep { const float* s[8]; u16* d[8]; };

// ---------------- one-time prep: cast x | transpose weights | zero cnt -----
__global__ __launch_bounds__(256) void prep_all(const float4* __restrict__ x4,
                                                ushort4* __restrict__ xb4,
                                                WPrep p, int* __restrict__ cnt) {
  const int bid = blockIdx.x;
  const int tid = threadIdx.x;
  if (bid < 5000) {
    int i = bid * 256 + tid;
    float4 v = x4[i];
    ushort4 o;
    o.x = f2bf(v.x); o.y = f2bf(v.y); o.z = f2bf(v.z); o.w = f2bf(v.w);
    xb4[i] = o;
  } else if (bid < 5128) {
    int b = bid - 5000;
    int m = b >> 4, xx = b & 15;
    int N = (m == 7) ? 64 : 128;
    int tiles_n = N / 32;
    int tx = xx % tiles_n, tk = xx / tiles_n;
    if (tk >= 4) return;
    __shared__ float t[32][33];
    int c = tid & 31, r8 = tid >> 5;
    const float* s = p.s[m];
    for (int rr = 0; rr < 32; rr += 8)
      t[rr + r8][c] = s[(size_t)(tk * 32 + rr + r8) * N + tx * 32 + c];
    __syncthreads();
    u16* d = p.d[m];
    for (int rr = 0; rr < 32; rr += 8)
      d[(size_t)(tx * 32 + rr + r8) * HD + tk * 32 + c] = f2bf(t[c][rr + r8]);
  } else {
    int i = (bid - 5128) * 256 + tid;
    if (i < NODES) cnt[i] = 0;
  }
}

// ---------------- bucket fill ----------------
__global__ __launch_bounds__(256) void bucket_fill(const int* __restrict__ ei,
                                                   int* __restrict__ cnt,
                                                   int* __restrict__ bucket) {
  int e = blockIdx.x * 256 + threadIdx.x;
  if (e >= EDGES) return;
  int s = ei[e];
  int d = ei[EDGES + e];
  int pos = atomicAdd(&cnt[d], 1);
  if (pos < CAP) bucket[d * CAP + pos] = s;
}

// ---- in-kernel gather, quarter-wave per node (best-measured config) ------
// Session evidence: gather is L2 random-line service-rate bound (~2.4M lines
// /layer at ~4 lines/cyc/XCD ~= 31us). Concurrency scaling is sub-linear
// (R3->R6), balancing neutral (R9), latency-hoisting neutral (R1), slicing
// negative (R4). This static quarter-wave config measured best (256.4us).
__device__ __forceinline__ void unpack_init(float* a, uint4 v) {
  a[0] = bf2f((u16)v.x); a[1] = bf2f((u16)(v.x >> 16));
  a[2] = bf2f((u16)v.y); a[3] = bf2f((u16)(v.y >> 16));
  a[4] = bf2f((u16)v.z); a[5] = bf2f((u16)(v.z >> 16));
  a[6] = bf2f((u16)v.w); a[7] = bf2f((u16)(v.w >> 16));
}
__device__ __forceinline__ void unpack_add(float* a, uint4 v) {
  a[0] += bf2f((u16)v.x); a[1] += bf2f((u16)(v.x >> 16));
  a[2] += bf2f((u16)v.y); a[3] += bf2f((u16)(v.y >> 16));
  a[4] += bf2f((u16)v.z); a[5] += bf2f((u16)(v.z >> 16));
  a[6] += bf2f((u16)v.w); a[7] += bf2f((u16)(v.w >> 16));
}

__device__ __forceinline__ void gather64(const u16* __restrict__ x,
                                         const int* __restrict__ cnt,
                                         const int* __restrict__ bucket,
                                         int node0, int tid,
                                         u16 (*L)[PK]) {
  const int ql = tid & 15;
  const int qw = tid >> 4;             // 0..15 quarter-waves
  for (int r = 0; r < 4; ++r) {
    const int brow = qw * 4 + r;       // 0..63
    const int node = node0 + brow;
    float a[8];
    if (node < NODES) {
      const int i0 = node * CAP;
      // three independent loads, issued back-to-back
      uint4 self = ((const uint4*)(x + (size_t)node * HD))[ql];
      int sv = bucket[i0 + ql];        // chunk-0 slots (ql<16<=CAP), no cnt dep
      int deg = cnt[node];
      if (deg > CAP) deg = CAP;
      unpack_init(a, self);
      for (int c0 = 0; c0 < deg; c0 += 16) {
        int m = deg - c0;
        if (m > 16) m = 16;
        for (int j = 0; j < m; j += 8) {
          int idx[8];
          uint4 uu[8];
#pragma unroll
          for (int jj = 0; jj < 8; ++jj) {
            int src = j + jj < m ? j + jj : 0;
            idx[jj] = __shfl(sv, src, 16);
          }
#pragma unroll
          for (int jj = 0; jj < 8; ++jj)
            uu[jj] = ((const uint4*)(x + (size_t)idx[jj] * HD))[ql];
#pragma unroll
          for (int jj = 0; jj < 8; ++jj)
            if (j + jj < m) unpack_add(a, uu[jj]);
        }
        int nc = c0 + 16;              // next slot chunk (deg>16); CAP clamp
        if (nc < deg) {
          int ad = nc + ql;
          sv = bucket[i0 + (ad < CAP ? ad : 0)];
        }
      }
    } else {
#pragma unroll
      for (int k = 0; k < 8; ++k) a[k] = 0.f;
    }
    uint4 pk;
    pk.x = (u32)f2bf(a[0]) | ((u32)f2bf(a[1]) << 16);
    pk.y = (u32)f2bf(a[2]) | ((u32)f2bf(a[3]) << 16);
    pk.z = (u32)f2bf(a[4]) | ((u32)f2bf(a[5]) << 16);
    pk.w = (u32)f2bf(a[6]) | ((u32)f2bf(a[7]) << 16);
    *(uint4*)&L[128 + brow][ql * 8] = pk;
  }
}

// ------------- fused layer: gather + ELU(BN(A@W1+b1))@W2+b2, ELU ----------
// LDS rows 0-127: weight (W1, then W2 re-staged); rows 128-191: per-wave
// strips (gathered A, then H). 52224B -> 3 blocks/CU. Grid 640 (64 rows/blk).
__global__ __launch_bounds__(256) void gin_layer(
    const u16* __restrict__ xin, const int* __restrict__ cnt,
    const int* __restrict__ bucket, const u16* __restrict__ W1t,
    const float* __restrict__ b1, const float* __restrict__ g,
    const float* __restrict__ bt, const float* __restrict__ mu,
    const float* __restrict__ vr, const u16* __restrict__ W2t,
    const float* __restrict__ b2, u16* __restrict__ xout) {
  __shared__ u16 L[192][PK];

  const int tid = threadIdx.x;
  const int wv = tid >> 6, lane = tid & 63;
  const int col = lane & 15, kg = lane >> 4;
  const int strip = blockIdx.x * 4 + wv;
  const int hrow = 128 + wv * 16;

  // stage W1 (loads issued first; latency hides under gather)
#pragma unroll
  for (int t = tid; t < 128 * 16; t += 256) {
    int r = t >> 4, c8 = t & 15;
    *(bf16x8*)&L[r][c8 * 8] = *(const bf16x8*)(W1t + (size_t)r * HD + c8 * 8);
  }
  gather64(xin, cnt, bucket, blockIdx.x * 64, tid, L);
  __syncthreads();

  // GEMM1 (A from LDS)
  f32x4 acc[8];
#pragma unroll
  for (int t = 0; t < 8; ++t) acc[t] = (f32x4){0.f, 0.f, 0.f, 0.f};
#pragma unroll
  for (int kk = 0; kk < HD; kk += 32) {
    bf16x8 av = *(const bf16x8*)&L[hrow + col][kk + kg * 8];
#pragma unroll
    for (int t = 0; t < 8; ++t) {
      bf16x8 bv = *(const bf16x8*)&L[t * 16 + col][kk + kg * 8];
      acc[t] = __builtin_amdgcn_mfma_f32_16x16x32_bf16(av, bv, acc[t], 0, 0, 0);
    }
  }
  __syncthreads();  // all waves done reading W1

  // stage W2 into rows 0-127; write H (BN+ELU) over own A strip
#pragma unroll
  for (int t = tid; t < 128 * 16; t += 256) {
    int r = t >> 4, c8 = t & 15;
    *(bf16x8*)&L[r][c8 * 8] = *(const bf16x8*)(W2t + (size_t)r * HD + c8 * 8);
  }
#pragma unroll
  for (int t = 0; t < 8; ++t) {
    int c = t * 16 + col;
    float rs = rsqrtf(vr[c] + BN_EPS) * g[c];
    float bb = bt[c] + (b1[c] - mu[c]) * rs;
#pragma unroll
    for (int r = 0; r < 4; ++r)
      L[hrow + kg * 4 + r][c] = f2bf(elu(acc[t][r] * rs + bb));
  }
  __syncthreads();

  // GEMM2
  f32x4 acc2[8];
#pragma unroll
  for (int t = 0; t < 8; ++t) acc2[t] = (f32x4){0.f, 0.f, 0.f, 0.f};
#pragma unroll
  for (int kk = 0; kk < HD; kk += 32) {
    bf16x8 av = *(const bf16x8*)&L[hrow + col][kk + kg * 8];
#pragma unroll
    for (int t = 0; t < 8; ++t) {
      bf16x8 bv = *(const bf16x8*)&L[t * 16 + col][kk + kg * 8];
      acc2[t] = __builtin_amdgcn_mfma_f32_16x16x32_bf16(av, bv, acc2[t], 0, 0, 0);
    }
  }
#pragma unroll
  for (int t = 0; t < 8; ++t) {
    int c = t * 16 + col;
    float bb = b2[c];
#pragma unroll
    for (int r = 0; r < 4; ++r)
      L[hrow + kg * 4 + r][c] = f2bf(elu(acc2[t][r] + bb));
  }
  {
    int r0 = lane >> 4, seg = lane & 15;
#pragma unroll
    for (int rr = 0; rr < 16; rr += 4) {
      int row = rr + r0;
      *(float4*)((char*)(xout + (size_t)(strip * 16 + row) * HD) + seg * 16) =
          *(const float4*)((const char*)&L[hrow + row][0] + seg * 16);
    }
  }
}

// ---- fused layer-3 + head: gather + 4 chained GEMMs ----------------------
__global__ __launch_bounds__(256) void gin_head(
    const u16* __restrict__ xin, const int* __restrict__ cnt,
    const int* __restrict__ bucket, const u16* __restrict__ W1t,
    const float* __restrict__ b1, const float* __restrict__ g,
    const float* __restrict__ bt, const float* __restrict__ mu,
    const float* __restrict__ vr, const u16* __restrict__ W2t,
    const float* __restrict__ b2, const u16* __restrict__ L1t,
    const float* __restrict__ lb1, const u16* __restrict__ L2t,
    const float* __restrict__ lb2, float* __restrict__ out) {
  __shared__ u16 L[192][PK];

  const int tid = threadIdx.x;
  const int wv = tid >> 6, lane = tid & 63;
  const int col = lane & 15, kg = lane >> 4;
  const int strip = blockIdx.x * 4 + wv;
  const int hrow = 128 + wv * 16;

#pragma unroll
  for (int t = tid; t < 128 * 16; t += 256) {
    int r = t >> 4, c8 = t & 15;
    *(bf16x8*)&L[r][c8 * 8] = *(const bf16x8*)(W1t + (size_t)r * HD + c8 * 8);
  }
  gather64(xin, cnt, bucket, blockIdx.x * 64, tid, L);
  __syncthreads();

  // GEMM1 (BN+ELU)
  f32x4 acc[8];
#pragma unroll
  for (int t = 0; t < 8; ++t) acc[t] = (f32x4){0.f, 0.f, 0.f, 0.f};
#pragma unroll
  for (int kk = 0; kk < HD; kk += 32) {
    bf16x8 av = *(const bf16x8*)&L[hrow + col][kk + kg * 8];
#pragma unroll
    for (int t = 0; t < 8; ++t) {
      bf16x8 bv = *(const bf16x8*)&L[t * 16 + col][kk + kg * 8];
      acc[t] = __builtin_amdgcn_mfma_f32_16x16x32_bf16(av, bv, acc[t], 0, 0, 0);
    }
  }
  __syncthreads();
#pragma unroll
  for (int t = tid; t < 128 * 16; t += 256) {   // stage W2
    int r = t >> 4, c8 = t & 15;
    *(bf16x8*)&L[r][c8 * 8] = *(const bf16x8*)(W2t + (size_t)r * HD + c8 * 8);
  }
#pragma unroll
  for (int t = 0; t < 8; ++t) {
    int c = t * 16 + col;
    float rs = rsqrtf(vr[c] + BN_EPS) * g[c];
    float bb = bt[c] + (b1[c] - mu[c]) * rs;
#pragma unroll
    for (int r = 0; r < 4; ++r)
      L[hrow + kg * 4 + r][c] = f2bf(elu(acc[t][r] * rs + bb));
  }
  __syncthreads();

  // GEMM2 (+b2, ELU)
#pragma unroll
  for (int t = 0; t < 8; ++t) acc[t] = (f32x4){0.f, 0.f, 0.f, 0.f};
#pragma unroll
  for (int kk = 0; kk < HD; kk += 32) {
    bf16x8 av = *(const bf16x8*)&L[hrow + col][kk + kg * 8];
#pragma unroll
    for (int t = 0; t < 8; ++t) {
      bf16x8 bv = *(const bf16x8*)&L[t * 16 + col][kk + kg * 8];
      acc[t] = __builtin_amdgcn_mfma_f32_16x16x32_bf16(av, bv, acc[t], 0, 0, 0);
    }
  }
  __syncthreads();
#pragma unroll
  for (int t = tid; t < 128 * 16; t += 256) {   // stage lin1
    int r = t >> 4, c8 = t & 15;
    *(bf16x8*)&L[r][c8 * 8] = *(const bf16x8*)(L1t + (size_t)r * HD + c8 * 8);
  }
#pragma unroll
  for (int t = 0; t < 8; ++t) {
    int c = t * 16 + col;
    float bb = b2[c];
#pragma unroll
    for (int r = 0; r < 4; ++r)
      L[hrow + kg * 4 + r][c] = f2bf(elu(acc[t][r] + bb));
  }
  __syncthreads();

  // LIN1 (+lb1, ELU)
#pragma unroll
  for (int t = 0; t < 8; ++t) acc[t] = (f32x4){0.f, 0.f, 0.f, 0.f};
#pragma unroll
  for (int kk = 0; kk < HD; kk += 32) {
    bf16x8 av = *(const bf16x8*)&L[hrow + col][kk + kg * 8];
#pragma unroll
    for (int t = 0; t < 8; ++t) {
      bf16x8 bv = *(const bf16x8*)&L[t * 16 + col][kk + kg * 8];
      acc[t] = __builtin_amdgcn_mfma_f32_16x16x32_bf16(av, bv, acc[t], 0, 0, 0);
    }
  }
  __syncthreads();
#pragma unroll
  for (int t = tid; t < 64 * 16; t += 256) {    // stage lin2 (64 rows)
    int r = t >> 4, c8 = t & 15;
    *(bf16x8*)&L[r][c8 * 8] = *(const bf16x8*)(L2t + (size_t)r * HD + c8 * 8);
  }
#pragma unroll
  for (int t = 0; t < 8; ++t) {
    int c = t * 16 + col;
    float bb = lb1[c];
#pragma unroll
    for (int r = 0; r < 4; ++r)
      L[hrow + kg * 4 + r][c] = f2bf(elu(acc[t][r] + bb));
  }
  __syncthreads();

  // LIN2 (+lb2) -> fp32 out [.][64]
  f32x4 acc2[4];
#pragma unroll
  for (int t = 0; t < 4; ++t) acc2[t] = (f32x4){0.f, 0.f, 0.f, 0.f};
#pragma unroll
  for (int kk = 0; kk < HD; kk += 32) {
    bf16x8 av = *(const bf16x8*)&L[hrow + col][kk + kg * 8];
#pragma unroll
    for (int t = 0; t < 4; ++t) {
      bf16x8 bv = *(const bf16x8*)&L[t * 16 + col][kk + kg * 8];
      acc2[t] = __builtin_amdgcn_mfma_f32_16x16x32_bf16(av, bv, acc2[t], 0, 0, 0);
    }
  }
#pragma unroll
  for (int t = 0; t < 4; ++t) {
    int c = t * 16 + col;
    float bb = lb2[c];
#pragma unroll
    for (int r = 0; r < 4; ++r)
      ((float*)&L[hrow + kg * 4 + r][0])[c] = acc2[t][r] + bb;
  }
  if (strip < NODES / 16) {            // real strips only (grid padded)
    int r0 = lane >> 4, seg = lane & 15;
#pragma unroll
    for (int rr = 0; rr < 16; rr += 4) {
      int row = rr + r0;
      *(float4*)((char*)(out + (size_t)(strip * 16 + row) * 64) + seg * 16) =
          *(const float4*)((const char*)&L[hrow + row][0] + seg * 16);
    }
  }
}

extern "C" void kernel_launch(void* const* d_in, const int* in_sizes, int n_in,
                              void* d_out, int out_size, void* d_ws, size_t ws_size,
                              hipStream_t stream) {
  const float* x = (const float*)d_in[0];
  const int* ei  = (const int*)d_in[1];
  const float* p[30];
  for (int i = 0; i < 30 && i < n_in; ++i) p[i] = (const float*)d_in[i];

  const size_t FEATP = (size_t)NPAD * HD;
  u16* xb0  = (u16*)d_ws;
  u16* xb1  = xb0 + FEATP;           // ping-pong
  u16* wt   = xb1 + FEATP;
  u16* wts[8];
  for (int m = 0; m < 8; ++m) wts[m] = wt + (size_t)m * HD * HD;
  int* cnt    = (int*)(wt + 8 * HD * HD);
  int* bucket = cnt + NODES;

  dim3 blk(256);
  const int edgeGrid = (EDGES + 255) / 256;   // 2344
  const int layerGrid = NPAD / 64;            // 640

  WPrep wp;
  const int widx[8] = {2, 8, 10, 16, 18, 24, 26, 28};
  for (int m = 0; m < 8; ++m) { wp.s[m] = p[widx[m]]; wp.d[m] = wts[m]; }
  prep_all<<<5285, blk, 0, stream>>>((const float4*)x, (ushort4*)xb0, wp, cnt);
  bucket_fill<<<edgeGrid, blk, 0, stream>>>(ei, cnt, bucket);

  gin_layer<<<layerGrid, blk, 0, stream>>>(
      xb0, cnt, bucket, wts[0], p[3], p[4], p[5], p[6], p[7], wts[1], p[9], xb1);
  gin_layer<<<layerGrid, blk, 0, stream>>>(
      xb1, cnt, bucket, wts[2], p[11], p[12], p[13], p[14], p[15], wts[3], p[17], xb0);
  gin_head<<<layerGrid, blk, 0, stream>>>(
      xb0, cnt, bucket, wts[4], p[19], p[20], p[21], p[22], p[23], wts[5], p[25],
      wts[6], p[27], wts[7], p[29], (float*)d_out);
}